// Round 17
// baseline (778.263 us; speedup 1.0000x reference)
//
#include <hip/hip_runtime.h>
#include <hip/hip_bf16.h>

#define NN 100000
#define NE 3200000
#define NB 512
#define BINW 128                  // nodes per bin (bin = node >> 7)
#define NBINS 782                 // ceil(NN / 128); 782*128 = 100096
#define EPB 8192                  // edges per p1/p3 block
#define NBLK 391                  // ceil(NE / EPB)
#define PK 3200                   // pool k-chunk (multiple of 128; 32*3200 = 102400 >= NN)
#define PNK 32

typedef unsigned short ushort_t;
typedef unsigned int uint_t;
typedef __attribute__((ext_vector_type(8))) short short8v;   // 8 bf16 (4 VGPRs)
typedef __attribute__((ext_vector_type(4))) float f32x4v;

static __device__ __forceinline__ short f2bf(float f) {
    __hip_bfloat16 h = __float2bfloat16(f);
    return *reinterpret_cast<short*>(&h);
}
static __device__ __forceinline__ float bf2f(ushort_t u) {
    return __uint_as_float(((uint_t)u) << 16);
}

// ---------------- p1: per-block bin-histograms (dst AND src), BOTH graphs ----------------
__global__ __launch_bounds__(256) void k_p1(const int* __restrict__ srcA,
                                            const int* __restrict__ dstA,
                                            const int* __restrict__ srcB,
                                            const int* __restrict__ dstB,
                                            int* __restrict__ cnt4,
                                            int* __restrict__ binTot) {
    __shared__ int hD[NBINS], hS[NBINS];
    int t = threadIdx.x, b = blockIdx.x;
    int g = (b >= NBLK) ? 1 : 0;
    int bb = b - g * NBLK;
    const int* src = g ? srcB : srcA;
    const int* dst = g ? dstB : dstA;
    int* cntD = cnt4 + (size_t)(2 * g)     * NBLK * NBINS;
    int* cntS = cnt4 + (size_t)(2 * g + 1) * NBLK * NBINS;
    int* btD  = binTot + (2 * g) * NBINS;
    int* btS  = binTot + (2 * g + 1) * NBINS;
    for (int i = t; i < NBINS; i += 256) { hD[i] = 0; hS[i] = 0; }
    __syncthreads();
    int base = bb * EPB;
#pragma unroll
    for (int i = 0; i < EPB / 1024; i++) {
        int idx = base + i * 1024 + t * 4;
        if (idx < NE) {  // NE%4==0 -> whole int4 valid
            int4 d4 = *(const int4*)(dst + idx);
            int4 s4 = *(const int4*)(src + idx);
            atomicAdd(&hD[d4.x >> 7], 1); atomicAdd(&hD[d4.y >> 7], 1);
            atomicAdd(&hD[d4.z >> 7], 1); atomicAdd(&hD[d4.w >> 7], 1);
            atomicAdd(&hS[s4.x >> 7], 1); atomicAdd(&hS[s4.y >> 7], 1);
            atomicAdd(&hS[s4.z >> 7], 1); atomicAdd(&hS[s4.w >> 7], 1);
        }
    }
    __syncthreads();
    for (int i = t; i < NBINS; i += 256) {
        int vD = hD[i]; cntD[(size_t)bb * NBINS + i] = vD; if (vD) atomicAdd(btD + i, vD);
        int vS = hS[i]; cntS[(size_t)bb * NBINS + i] = vS; if (vS) atomicAdd(btS + i, vS);
    }
}

// ---------------- scanA: exclusive scan of bin totals, 4 units ----------------
__global__ void k_scanA(const int* __restrict__ binTot, int* __restrict__ binBase,
                        int* __restrict__ off_su, int* __restrict__ off_sv) {
    __shared__ int s[NBINS];
    int u = blockIdx.x;  // 0=D_su 1=S_su 2=D_sv 3=S_sv
    const int* bt = binTot + u * NBINS;
    int* bb = binBase + u * (NBINS + 1);
    int t = threadIdx.x;
    for (int i = t; i < NBINS; i += 256) s[i] = bt[i];
    __syncthreads();
    if (t == 0) {
        int acc = 0;
        for (int i = 0; i < NBINS; i++) { int v = s[i]; s[i] = acc; acc += v; }
    }
    __syncthreads();
    for (int i = t; i < NBINS; i += 256) bb[i] = s[i];
    if (t == 0) bb[NBINS] = NE;
    if (t == 0 && u == 0) { off_su[NN] = NE; off_sv[NN] = NE; }
}

// ---------------- scanB: per-bin prefix over blocks, IN PLACE in cnt ----------------
__global__ void k_scanB(int* __restrict__ cnt4, const int* __restrict__ binBase) {
    __shared__ int s[NBLK];
    int u = blockIdx.x / NBINS, j = blockIdx.x % NBINS;
    int* cnt = cnt4 + (size_t)u * NBLK * NBINS;
    const int* bb = binBase + u * (NBINS + 1);
    int t = threadIdx.x;
    for (int i = t; i < NBLK; i += 256) s[i] = cnt[(size_t)i * NBINS + j];
    __syncthreads();
    if (t == 0) {
        int acc = bb[j];
        for (int i = 0; i < NBLK; i++) { int v = s[i]; s[i] = acc; acc += v; }
    }
    __syncthreads();
    for (int i = t; i < NBLK; i += 256) cnt[(size_t)i * NBINS + j] = s[i];
}

// ---------------- p3: dual scatter into bin order (coalesced cursor loads) ----------------
__global__ __launch_bounds__(256) void k_p3(const int* __restrict__ src,
                                            const int* __restrict__ dst,
                                            const int* __restrict__ cntD,
                                            const int* __restrict__ cntS,
                                            int2* __restrict__ sortedD,
                                            int* __restrict__ sortedS) {
    __shared__ int curD[NBINS], curS[NBINS];
    int t = threadIdx.x, b = blockIdx.x;
    for (int i = t; i < NBINS; i += 256) {
        curD[i] = cntD[(size_t)b * NBINS + i];
        curS[i] = cntS[(size_t)b * NBINS + i];
    }
    __syncthreads();
    int base = b * EPB;
#pragma unroll
    for (int i = 0; i < EPB / 1024; i++) {
        int idx = base + i * 1024 + t * 4;
        if (idx < NE) {
            int4 s4 = *(const int4*)(src + idx);
            int4 d4 = *(const int4*)(dst + idx);
            int p;
            p = atomicAdd(&curD[d4.x >> 7], 1); sortedD[p] = make_int2(s4.x, d4.x);
            p = atomicAdd(&curD[d4.y >> 7], 1); sortedD[p] = make_int2(s4.y, d4.y);
            p = atomicAdd(&curD[d4.z >> 7], 1); sortedD[p] = make_int2(s4.z, d4.z);
            p = atomicAdd(&curD[d4.w >> 7], 1); sortedD[p] = make_int2(s4.w, d4.w);
            p = atomicAdd(&curS[s4.x >> 7], 1); sortedS[p] = s4.x;
            p = atomicAdd(&curS[s4.y >> 7], 1); sortedS[p] = s4.y;
            p = atomicAdd(&curS[s4.z >> 7], 1); sortedS[p] = s4.z;
            p = atomicAdd(&curS[s4.w >> 7], 1); sortedS[p] = s4.w;
        }
    }
}

// ---------------- p4 merged: [0,NBINS) counting-sort -> CSR; [NBINS,2N) src-hist ----------------
__global__ __launch_bounds__(256) void k_p4(const int2* __restrict__ sortedD,
                                            const int* __restrict__ sortedS,
                                            const int* __restrict__ bbD,
                                            const int* __restrict__ bbS,
                                            int* __restrict__ off,
                                            int* __restrict__ edges,
                                            int* __restrict__ cnt_src) {
    __shared__ int hist[BINW], pre[BINW], cur[BINW];
    int t = threadIdx.x;
    if (blockIdx.x < NBINS) {
        int bin = blockIdx.x;
        if (t < BINW) hist[t] = 0;
        __syncthreads();
        int e0 = bbD[bin], e1 = bbD[bin + 1];
        for (int e = e0 + t; e < e1; e += 256)
            atomicAdd(&hist[sortedD[e].y & (BINW - 1)], 1);
        __syncthreads();
        if (t == 0) {
            int a = 0;
            for (int i = 0; i < BINW; i++) { pre[i] = a; a += hist[i]; }
        }
        __syncthreads();
        if (t < BINW) {
            cur[t] = pre[t];
            int node = bin * BINW + t;
            if (node < NN) off[node] = e0 + pre[t];
        }
        __syncthreads();
        for (int e = e0 + t; e < e1; e += 256) {
            int2 ed = sortedD[e];
            int p = atomicAdd(&cur[ed.y & (BINW - 1)], 1);
            edges[e0 + p] = ed.x;
        }
    } else {
        int bin = blockIdx.x - NBINS;
        if (t < BINW) hist[t] = 0;
        __syncthreads();
        int e0 = bbS[bin], e1 = bbS[bin + 1];
        for (int e = e0 + t; e < e1; e += 256)
            atomicAdd(&hist[sortedS[e] & (BINW - 1)], 1);
        __syncthreads();
        if (t < BINW) {
            int node = bin * BINW + t;
            if (node < NN) cnt_src[node] = hist[t];
        }
    }
}

// ---------------- t1: y = (x*sn)@W1 (bf16) ----------------
__global__ __launch_bounds__(256) void k_t1(const float* __restrict__ x,
                                            const float* __restrict__ W1,
                                            const int* __restrict__ cnt_src,
                                            ushort_t* __restrict__ y) {
    __shared__ float sW[2048];
    __shared__ float sx[8 * 65];
    int t = threadIdx.x;
    int node0 = blockIdx.x * 8;
    for (int i = t; i < 2048; i += 256) sW[i] = W1[i];
    for (int i = t; i < 512; i += 256) {
        int r = i >> 6, k = i & 63;
        sx[r * 65 + k] = x[(size_t)(node0 + r) * 64 + k];
    }
    __syncthreads();
    int r = t >> 5, c = t & 31;
    int node = node0 + r;
    float sn = rsqrtf(fmaxf((float)cnt_src[node], 1.0f));
    float acc = 0.0f;
#pragma unroll
    for (int k = 0; k < 64; k++) acc += sx[r * 65 + k] * sW[k * 32 + c];
    acc *= sn;   // row scalar commutes with @W1
    y[(size_t)node * 32 + c] = (ushort_t)f2bf(acc);
}

// ---------------- t2: y2 = (HTb_rows(0..31)*sn)@W2 (bf16 in, bf16 out) ----------------
__global__ __launch_bounds__(256) void k_t2(const ushort_t* __restrict__ HTb,
                                            const float* __restrict__ W2,
                                            const int* __restrict__ cnt_src,
                                            ushort_t* __restrict__ y2) {
    __shared__ float sW[512];
    __shared__ float sx[16 * 33];
    int t = threadIdx.x;
    int node0 = blockIdx.x * 16;
    for (int i = t; i < 512; i += 256) sW[i] = W2[i];
    for (int i = t; i < 512; i += 256) {
        int r = i & 15, k = i >> 4;  // r fast -> coalesced over node dim
        sx[r * 33 + k] = bf2f(HTb[(size_t)k * NN + node0 + r]);
    }
    __syncthreads();
    int r = t >> 4, c = t & 15;
    int node = node0 + r;
    float sn = rsqrtf(fmaxf((float)cnt_src[node], 1.0f));
    float acc = 0.0f;
#pragma unroll
    for (int k = 0; k < 32; k++) acc += sx[r * 33 + k] * sW[k * 16 + c];
    acc *= sn;
    y2[(size_t)node * 16 + c] = (ushort_t)f2bf(acc);
}

// ---------------- CSR gather aggregation, packed-uint y, bf16 HTb output ----------------
template <int F, int RELU>
__global__ __launch_bounds__(256) void k_agg(
        const uint_t* __restrict__ y, const int* __restrict__ off,
        const int* __restrict__ edges, const float* __restrict__ bias,
        ushort_t* __restrict__ HTb, int coloff) {
    constexpr int L = F / 2;
    constexpr int NPB = 256 / L;
    int t = threadIdx.x;
    int g = t / L, c2 = t % L;
    int node = blockIdx.x * NPB + g;
    int e0 = off[node], e1 = off[node + 1];
    int deg = e1 - e0;
    const int* srow = edges + e0;
    float a0 = 0.0f, a1 = 0.0f;
    int e = 0;
    for (; e + 3 < deg; e += 4) {
        int s0 = srow[e], s1 = srow[e + 1], s2 = srow[e + 2], s3 = srow[e + 3];
        uint_t u0 = y[(size_t)s0 * L + c2];
        uint_t u1 = y[(size_t)s1 * L + c2];
        uint_t u2 = y[(size_t)s2 * L + c2];
        uint_t u3 = y[(size_t)s3 * L + c2];
        a0 += __uint_as_float(u0 << 16) + __uint_as_float(u1 << 16)
            + __uint_as_float(u2 << 16) + __uint_as_float(u3 << 16);
        a1 += __uint_as_float(u0 & 0xFFFF0000u) + __uint_as_float(u1 & 0xFFFF0000u)
            + __uint_as_float(u2 & 0xFFFF0000u) + __uint_as_float(u3 & 0xFFFF0000u);
    }
    for (; e < deg; e++) {
        uint_t u = y[(size_t)srow[e] * L + c2];
        a0 += __uint_as_float(u << 16);
        a1 += __uint_as_float(u & 0xFFFF0000u);
    }
    float dn = rsqrtf(fmaxf((float)deg, 1.0f));
    float v0 = a0 * dn + bias[2 * c2];
    float v1 = a1 * dn + bias[2 * c2 + 1];
    if (RELU) { v0 = fmaxf(v0, 0.0f); v1 = fmaxf(v1, 0.0f); }
    HTb[(size_t)(coloff + 2 * c2) * NN + node] = (ushort_t)f2bf(v0);
    HTb[(size_t)(coloff + 2 * c2 + 1) * NN + node] = (ushort_t)f2bf(v1);
}

// ---------------- pooling v11: MFMA, 2048 blocks + deep unroll for MLP ----------------
// r16: guard-free loop landed 2.1TB/s but VGPR=28 (compiler kept only ~6 loads in flight)
// and 1024 blocks = 24 waves/CU demand (occ 53%). Fixes: PNK 16->32 (2048 blocks = 48
// waves/CU demand -> saturates the 32-wave cap) and #pragma unroll 4 (24 indep loads per
// wave iteration; VGPR ~60-80 still occupancy-safe).
// Frag layouts (guide §3, m89-verified): A lane l -> row l&15, k=(l>>4)*8+i; B lane l ->
// col l&15, same k; C/D lane l reg r -> row (l>>4)*4+r, col l&15.
__global__ __launch_bounds__(384) void k_pool9(
        const float* __restrict__ lenA, const float* __restrict__ lenB,
        const ushort_t* __restrict__ HTbA, const ushort_t* __restrict__ HTbB,
        float* __restrict__ pooled) {
    __shared__ float red[3][64][4];
    const int mat = blockIdx.z;
    const float* __restrict__ len = mat ? lenB : lenA;
    const ushort_t* __restrict__ HTb = mat ? HTbB : HTbA;
    const int colbase = mat ? 48 : 0;
    const int b0 = blockIdx.x * 16;
    const int w = threadIdx.x >> 6;   // 0..5
    const int l = threadIdx.x & 63;
    const int c = w >> 1;             // col tile 0..2
    const int kh = w & 1;             // k-partner (even/odd 64-k blocks)
    const int rc = l & 15;
    const int seg = l >> 4;           // 0..3

    const int kc0 = blockIdx.y * PK;
    const int kend = (kc0 + PK < NN) ? (kc0 + PK) : NN;
    const float* lrow = len + (size_t)(b0 + rc) * NN;          // A row (graph b0+rc)
    const ushort_t* hrow = HTb + (size_t)(c * 16 + rc) * NN;   // B col (HTb row)

    f32x4v acc = {0.0f, 0.0f, 0.0f, 0.0f};

    const int kw0 = kc0 + kh * 64;            // this wave's first 64-k halfstep
    const int lb0 = kw0 + seg * 8;            // this lane's base
    int avail = kend - kw0;
    int Tfull = (avail >= 64) ? ((avail - 64) >> 7) + 1 : 0;  // halfsteps fully in range

#pragma unroll 4
    for (int t = 0; t < Tfull; t++) {
        int kb = lb0 + t * 128;
#pragma unroll
        for (int h = 0; h < 2; h++) {
            f32x4v a0 = *(const f32x4v*)(lrow + kb + h * 32);
            f32x4v a1 = *(const f32x4v*)(lrow + kb + h * 32 + 4);
            short8v b = *(const short8v*)(hrow + kb + h * 32);
            short8v a;
            a[0] = f2bf(a0.x); a[1] = f2bf(a0.y); a[2] = f2bf(a0.z); a[3] = f2bf(a0.w);
            a[4] = f2bf(a1.x); a[5] = f2bf(a1.y); a[6] = f2bf(a1.z); a[7] = f2bf(a1.w);
            acc = __builtin_amdgcn_mfma_f32_16x16x32_bf16(a, b, acc, 0, 0, 0);
        }
    }

    // guarded tail halfstep (only the last k-chunk reaches here); 8|NN and 8|kend ->
    // a lane's 8-seg is valid iff kb < kend
    int kt = kw0 + Tfull * 128;
    if (kt < kend) {
#pragma unroll
        for (int h = 0; h < 2; h++) {
            int kb = kt + h * 32 + seg * 8;
            short8v a = (short8v)0, b = (short8v)0;
            if (kb < kend) {
                f32x4v a0 = *(const f32x4v*)(lrow + kb);
                f32x4v a1 = *(const f32x4v*)(lrow + kb + 4);
                a[0] = f2bf(a0.x); a[1] = f2bf(a0.y); a[2] = f2bf(a0.z); a[3] = f2bf(a0.w);
                a[4] = f2bf(a1.x); a[5] = f2bf(a1.y); a[6] = f2bf(a1.z); a[7] = f2bf(a1.w);
                b = *(const short8v*)(hrow + kb);
            }
            acc = __builtin_amdgcn_mfma_f32_16x16x32_bf16(a, b, acc, 0, 0, 0);
        }
    }

    if (kh == 1) {
        *(f32x4v*)&red[c][l][0] = acc;
    }
    __syncthreads();
    if (kh == 0) {
        f32x4v o = *(const f32x4v*)&red[c][l][0];
#pragma unroll
        for (int r = 0; r < 4; r++) {
            float v = acc[r] + o[r];
            atomicAdd(&pooled[(b0 + seg * 4 + r) * 96 + colbase + c * 16 + rc], v);
        }
    }
}

// ---------------- MLP head ----------------
__global__ void k_mlp(const float* __restrict__ pooled,
                      const float* __restrict__ fc1w, const float* __restrict__ fc1b,
                      const float* __restrict__ fc2w, const float* __restrict__ fc2b,
                      const float* __restrict__ fc3w, const float* __restrict__ fc3b,
                      float* __restrict__ out) {
    __shared__ float srow[96];
    __shared__ float sh[64];
    __shared__ float sh2[16];
    int b = blockIdx.x, t = threadIdx.x; // 64 threads
    srow[t] = pooled[b * 96 + t];
    if (t < 32) srow[64 + t] = pooled[b * 96 + 64 + t];
    __syncthreads();
    float acc = fc1b[t];
    for (int k = 0; k < 96; k++) acc += srow[k] * fc1w[k * 64 + t];
    sh[t] = fmaxf(acc, 0.0f);
    __syncthreads();
    if (t < 16) {
        float a2 = fc2b[t];
        for (int k = 0; k < 64; k++) a2 += sh[k] * fc2w[k * 16 + t];
        sh2[t] = fmaxf(a2, 0.0f);
    }
    __syncthreads();
    if (t == 0) {
        float a3 = fc3b[0];
        for (int k = 0; k < 16; k++) a3 += sh2[k] * fc3w[k];
        out[b] = a3;
    }
}

extern "C" void kernel_launch(void* const* d_in, const int* in_sizes, int n_in,
                              void* d_out, int out_size, void* d_ws, size_t ws_size,
                              hipStream_t stream) {
    const float* solute_x  = (const float*)d_in[0];
    const float* solvent_x = (const float*)d_in[1];
    const float* su_len    = (const float*)d_in[2];
    const float* sv_len    = (const float*)d_in[3];
    const int*   su_src    = (const int*)d_in[4];
    const int*   su_dst    = (const int*)d_in[5];
    const int*   sv_src    = (const int*)d_in[6];
    const int*   sv_dst    = (const int*)d_in[7];
    const float* W1  = (const float*)d_in[8];
    const float* b1  = (const float*)d_in[9];
    const float* W2  = (const float*)d_in[10];
    const float* b2  = (const float*)d_in[11];
    const float* fc1w = (const float*)d_in[12];
    const float* fc1b = (const float*)d_in[13];
    const float* fc2w = (const float*)d_in[14];
    const float* fc2b = (const float*)d_in[15];
    const float* fc3w = (const float*)d_in[16];
    const float* fc3b = (const float*)d_in[17];
    float* out = (float*)d_out;

    // ---- arena (4B words), total ~70.8 MB ----
    char* ws = (char*)d_ws;
    size_t o = 0;
    auto alloc = [&](size_t elems) { void* p = ws + o * 4; o += elems; return p; };
    int* cnt4     = (int*)alloc((size_t)4 * NBLK * NBINS);  // [D_su][S_su][D_sv][S_sv]
    int* binTot   = (int*)alloc(4 * NBINS);
    int* binBase  = (int*)alloc(4 * (NBINS + 1));
    int* off_su   = (int*)alloc(NN + 1);
    int* off_sv   = (int*)alloc(NN + 1);
    int* csrc_su  = (int*)alloc(NN);
    int* csrc_sv  = (int*)alloc(NN);
    float* pooled = (float*)alloc(NB * 96);
    int* edges_su = (int*)alloc(NE);
    int* edges_sv = (int*)alloc(NE);
    o = (o + 1) & ~(size_t)1;                 // 8B align for int2
    // union region X: build {sortedD int2 NE = 25.6MB, sortedS int NE = 12.8MB} = 38.4MB
    //                 compute {ybuf 6.4MB + HTb_su 9.6MB + HTb_sv 9.6MB} = 25.6MB
    char* X = ws + o * 4;
    int2*     sortedD = (int2*)X;
    int*      sortedS = (int*)(X + (size_t)NE * 8);
    uint_t*   ybuf    = (uint_t*)X;
    ushort_t* HTb_su  = (ushort_t*)(X + (size_t)NN * 64);
    ushort_t* HTb_sv  = (ushort_t*)(X + (size_t)NN * 160);

    hipMemsetAsync(binTot, 0, 4 * NBINS * 4, stream);
    hipMemsetAsync(pooled, 0, NB * 96 * 4, stream);

    // ==== phase 1: histograms + scans for BOTH graphs in merged launches ====
    k_p1<<<2 * NBLK, 256, 0, stream>>>(su_src, su_dst, sv_src, sv_dst, cnt4, binTot);
    k_scanA<<<4, 256, 0, stream>>>(binTot, binBase, off_su, off_sv);
    k_scanB<<<4 * NBINS, 256, 0, stream>>>(cnt4, binBase);

    const int* g_src[2]  = {su_src, sv_src};
    const int* g_dst[2]  = {su_dst, sv_dst};
    int* g_off[2]        = {off_su, off_sv};
    int* g_edges[2]      = {edges_su, edges_sv};
    int* g_csrc[2]       = {csrc_su, csrc_sv};

    // per-graph: scatter + counting-sort (sorted buffers reused sequentially)
    for (int g = 0; g < 2; g++) {
        const int* cntD = cnt4 + (size_t)(2 * g) * NBLK * NBINS;
        const int* cntS = cnt4 + (size_t)(2 * g + 1) * NBLK * NBINS;
        const int* bbD  = binBase + (2 * g) * (NBINS + 1);
        const int* bbS  = binBase + (2 * g + 1) * (NBINS + 1);
        k_p3<<<NBLK, 256, 0, stream>>>(g_src[g], g_dst[g], cntD, cntS, sortedD, sortedS);
        k_p4<<<2 * NBINS, 256, 0, stream>>>(sortedD, sortedS, bbD, bbS,
                                            g_off[g], g_edges[g], g_csrc[g]);
    }

    // ==== phase 2: GCN layers (sorted buffers dead; ybuf/HTb take over region X) ====
    const float* g_x[2]  = {solute_x, solvent_x};
    ushort_t* g_HTb[2]   = {HTb_su, HTb_sv};
    for (int g = 0; g < 2; g++) {
        k_t1<<<NN / 8, 256, 0, stream>>>(g_x[g], W1, g_csrc[g], (ushort_t*)ybuf);
        k_agg<32, 1><<<NN / 16, 256, 0, stream>>>(ybuf, g_off[g], g_edges[g], b1, g_HTb[g], 0);
        k_t2<<<NN / 16, 256, 0, stream>>>(g_HTb[g], W2, g_csrc[g], (ushort_t*)ybuf);
        k_agg<16, 0><<<NN / 32, 256, 0, stream>>>(ybuf, g_off[g], g_edges[g], b2, g_HTb[g], 32);
    }

    // ==== pooling (MFMA) + MLP ====
    {
        dim3 gr(NB / 16, PNK, 2);
        k_pool9<<<gr, 384, 0, stream>>>(su_len, sv_len, HTb_su, HTb_sv, pooled);
    }
    k_mlp<<<NB, 64, 0, stream>>>(pooled, fc1w, fc1b, fc2w, fc2b, fc3w, fc3b, out);
}

// Round 18
// 775.425 us; speedup vs baseline: 1.0037x; 1.0037x over previous
//
#include <hip/hip_runtime.h>
#include <hip/hip_bf16.h>

#define NN 100000
#define NE 3200000
#define NB 512
#define BINW 128                  // nodes per bin (bin = node >> 7)
#define NBINS 782                 // ceil(NN / 128); 782*128 = 100096
#define EPB 8192                  // edges per p1/p3 block
#define NBLK 391                  // ceil(NE / EPB)
#define PK 3200                   // pool k-chunk (multiple of 128; 32*3200 = 102400 >= NN)
#define PNK 32

typedef unsigned short ushort_t;
typedef unsigned int uint_t;
typedef __attribute__((ext_vector_type(8))) short short8v;   // 8 bf16 (4 VGPRs)
typedef __attribute__((ext_vector_type(4))) float f32x4v;

static __device__ __forceinline__ short f2bf(float f) {
    __hip_bfloat16 h = __float2bfloat16(f);
    return *reinterpret_cast<short*>(&h);
}
static __device__ __forceinline__ float bf2f(ushort_t u) {
    return __uint_as_float(((uint_t)u) << 16);
}

// ---------------- p1: per-block bin-histograms (dst AND src), BOTH graphs ----------------
__global__ __launch_bounds__(256) void k_p1(const int* __restrict__ srcA,
                                            const int* __restrict__ dstA,
                                            const int* __restrict__ srcB,
                                            const int* __restrict__ dstB,
                                            int* __restrict__ cnt4,
                                            int* __restrict__ binTot) {
    __shared__ int hD[NBINS], hS[NBINS];
    int t = threadIdx.x, b = blockIdx.x;
    int g = (b >= NBLK) ? 1 : 0;
    int bb = b - g * NBLK;
    const int* src = g ? srcB : srcA;
    const int* dst = g ? dstB : dstA;
    int* cntD = cnt4 + (size_t)(2 * g)     * NBLK * NBINS;
    int* cntS = cnt4 + (size_t)(2 * g + 1) * NBLK * NBINS;
    int* btD  = binTot + (2 * g) * NBINS;
    int* btS  = binTot + (2 * g + 1) * NBINS;
    for (int i = t; i < NBINS; i += 256) { hD[i] = 0; hS[i] = 0; }
    __syncthreads();
    int base = bb * EPB;
#pragma unroll
    for (int i = 0; i < EPB / 1024; i++) {
        int idx = base + i * 1024 + t * 4;
        if (idx < NE) {  // NE%4==0 -> whole int4 valid
            int4 d4 = *(const int4*)(dst + idx);
            int4 s4 = *(const int4*)(src + idx);
            atomicAdd(&hD[d4.x >> 7], 1); atomicAdd(&hD[d4.y >> 7], 1);
            atomicAdd(&hD[d4.z >> 7], 1); atomicAdd(&hD[d4.w >> 7], 1);
            atomicAdd(&hS[s4.x >> 7], 1); atomicAdd(&hS[s4.y >> 7], 1);
            atomicAdd(&hS[s4.z >> 7], 1); atomicAdd(&hS[s4.w >> 7], 1);
        }
    }
    __syncthreads();
    for (int i = t; i < NBINS; i += 256) {
        int vD = hD[i]; cntD[(size_t)bb * NBINS + i] = vD; if (vD) atomicAdd(btD + i, vD);
        int vS = hS[i]; cntS[(size_t)bb * NBINS + i] = vS; if (vS) atomicAdd(btS + i, vS);
    }
}

// ---------------- scanA: exclusive scan of bin totals, 4 units ----------------
__global__ void k_scanA(const int* __restrict__ binTot, int* __restrict__ binBase,
                        int* __restrict__ off_su, int* __restrict__ off_sv) {
    __shared__ int s[NBINS];
    int u = blockIdx.x;  // 0=D_su 1=S_su 2=D_sv 3=S_sv
    const int* bt = binTot + u * NBINS;
    int* bb = binBase + u * (NBINS + 1);
    int t = threadIdx.x;
    for (int i = t; i < NBINS; i += 256) s[i] = bt[i];
    __syncthreads();
    if (t == 0) {
        int acc = 0;
        for (int i = 0; i < NBINS; i++) { int v = s[i]; s[i] = acc; acc += v; }
    }
    __syncthreads();
    for (int i = t; i < NBINS; i += 256) bb[i] = s[i];
    if (t == 0) bb[NBINS] = NE;
    if (t == 0 && u == 0) { off_su[NN] = NE; off_sv[NN] = NE; }
}

// ---------------- scanB: per-bin prefix over blocks, IN PLACE in cnt ----------------
__global__ void k_scanB(int* __restrict__ cnt4, const int* __restrict__ binBase) {
    __shared__ int s[NBLK];
    int u = blockIdx.x / NBINS, j = blockIdx.x % NBINS;
    int* cnt = cnt4 + (size_t)u * NBLK * NBINS;
    const int* bb = binBase + u * (NBINS + 1);
    int t = threadIdx.x;
    for (int i = t; i < NBLK; i += 256) s[i] = cnt[(size_t)i * NBINS + j];
    __syncthreads();
    if (t == 0) {
        int acc = bb[j];
        for (int i = 0; i < NBLK; i++) { int v = s[i]; s[i] = acc; acc += v; }
    }
    __syncthreads();
    for (int i = t; i < NBLK; i += 256) cnt[(size_t)i * NBINS + j] = s[i];
}

// ---------------- p3: dual scatter into bin order (coalesced cursor loads) ----------------
__global__ __launch_bounds__(256) void k_p3(const int* __restrict__ src,
                                            const int* __restrict__ dst,
                                            const int* __restrict__ cntD,
                                            const int* __restrict__ cntS,
                                            int2* __restrict__ sortedD,
                                            int* __restrict__ sortedS) {
    __shared__ int curD[NBINS], curS[NBINS];
    int t = threadIdx.x, b = blockIdx.x;
    for (int i = t; i < NBINS; i += 256) {
        curD[i] = cntD[(size_t)b * NBINS + i];
        curS[i] = cntS[(size_t)b * NBINS + i];
    }
    __syncthreads();
    int base = b * EPB;
#pragma unroll
    for (int i = 0; i < EPB / 1024; i++) {
        int idx = base + i * 1024 + t * 4;
        if (idx < NE) {
            int4 s4 = *(const int4*)(src + idx);
            int4 d4 = *(const int4*)(dst + idx);
            int p;
            p = atomicAdd(&curD[d4.x >> 7], 1); sortedD[p] = make_int2(s4.x, d4.x);
            p = atomicAdd(&curD[d4.y >> 7], 1); sortedD[p] = make_int2(s4.y, d4.y);
            p = atomicAdd(&curD[d4.z >> 7], 1); sortedD[p] = make_int2(s4.z, d4.z);
            p = atomicAdd(&curD[d4.w >> 7], 1); sortedD[p] = make_int2(s4.w, d4.w);
            p = atomicAdd(&curS[s4.x >> 7], 1); sortedS[p] = s4.x;
            p = atomicAdd(&curS[s4.y >> 7], 1); sortedS[p] = s4.y;
            p = atomicAdd(&curS[s4.z >> 7], 1); sortedS[p] = s4.z;
            p = atomicAdd(&curS[s4.w >> 7], 1); sortedS[p] = s4.w;
        }
    }
}

// ---------------- p4 merged: [0,NBINS) counting-sort -> CSR; [NBINS,2N) src-hist ----------------
__global__ __launch_bounds__(256) void k_p4(const int2* __restrict__ sortedD,
                                            const int* __restrict__ sortedS,
                                            const int* __restrict__ bbD,
                                            const int* __restrict__ bbS,
                                            int* __restrict__ off,
                                            int* __restrict__ edges,
                                            int* __restrict__ cnt_src) {
    __shared__ int hist[BINW], pre[BINW], cur[BINW];
    int t = threadIdx.x;
    if (blockIdx.x < NBINS) {
        int bin = blockIdx.x;
        if (t < BINW) hist[t] = 0;
        __syncthreads();
        int e0 = bbD[bin], e1 = bbD[bin + 1];
        for (int e = e0 + t; e < e1; e += 256)
            atomicAdd(&hist[sortedD[e].y & (BINW - 1)], 1);
        __syncthreads();
        if (t == 0) {
            int a = 0;
            for (int i = 0; i < BINW; i++) { pre[i] = a; a += hist[i]; }
        }
        __syncthreads();
        if (t < BINW) {
            cur[t] = pre[t];
            int node = bin * BINW + t;
            if (node < NN) off[node] = e0 + pre[t];
        }
        __syncthreads();
        for (int e = e0 + t; e < e1; e += 256) {
            int2 ed = sortedD[e];
            int p = atomicAdd(&cur[ed.y & (BINW - 1)], 1);
            edges[e0 + p] = ed.x;
        }
    } else {
        int bin = blockIdx.x - NBINS;
        if (t < BINW) hist[t] = 0;
        __syncthreads();
        int e0 = bbS[bin], e1 = bbS[bin + 1];
        for (int e = e0 + t; e < e1; e += 256)
            atomicAdd(&hist[sortedS[e] & (BINW - 1)], 1);
        __syncthreads();
        if (t < BINW) {
            int node = bin * BINW + t;
            if (node < NN) cnt_src[node] = hist[t];
        }
    }
}

// ---------------- t1: y = (x*sn)@W1 (bf16) ----------------
__global__ __launch_bounds__(256) void k_t1(const float* __restrict__ x,
                                            const float* __restrict__ W1,
                                            const int* __restrict__ cnt_src,
                                            ushort_t* __restrict__ y) {
    __shared__ float sW[2048];
    __shared__ float sx[8 * 65];
    int t = threadIdx.x;
    int node0 = blockIdx.x * 8;
    for (int i = t; i < 2048; i += 256) sW[i] = W1[i];
    for (int i = t; i < 512; i += 256) {
        int r = i >> 6, k = i & 63;
        sx[r * 65 + k] = x[(size_t)(node0 + r) * 64 + k];
    }
    __syncthreads();
    int r = t >> 5, c = t & 31;
    int node = node0 + r;
    float sn = rsqrtf(fmaxf((float)cnt_src[node], 1.0f));
    float acc = 0.0f;
#pragma unroll
    for (int k = 0; k < 64; k++) acc += sx[r * 65 + k] * sW[k * 32 + c];
    acc *= sn;   // row scalar commutes with @W1
    y[(size_t)node * 32 + c] = (ushort_t)f2bf(acc);
}

// ---------------- t2: y2 = (HTb_rows(0..31)*sn)@W2 (bf16 in, bf16 out) ----------------
__global__ __launch_bounds__(256) void k_t2(const ushort_t* __restrict__ HTb,
                                            const float* __restrict__ W2,
                                            const int* __restrict__ cnt_src,
                                            ushort_t* __restrict__ y2) {
    __shared__ float sW[512];
    __shared__ float sx[16 * 33];
    int t = threadIdx.x;
    int node0 = blockIdx.x * 16;
    for (int i = t; i < 512; i += 256) sW[i] = W2[i];
    for (int i = t; i < 512; i += 256) {
        int r = i & 15, k = i >> 4;  // r fast -> coalesced over node dim
        sx[r * 33 + k] = bf2f(HTb[(size_t)k * NN + node0 + r]);
    }
    __syncthreads();
    int r = t >> 4, c = t & 15;
    int node = node0 + r;
    float sn = rsqrtf(fmaxf((float)cnt_src[node], 1.0f));
    float acc = 0.0f;
#pragma unroll
    for (int k = 0; k < 32; k++) acc += sx[r * 33 + k] * sW[k * 16 + c];
    acc *= sn;
    y2[(size_t)node * 16 + c] = (ushort_t)f2bf(acc);
}

// ---------------- CSR gather aggregation, packed-uint y, bf16 HTb output ----------------
template <int F, int RELU>
__global__ __launch_bounds__(256) void k_agg(
        const uint_t* __restrict__ y, const int* __restrict__ off,
        const int* __restrict__ edges, const float* __restrict__ bias,
        ushort_t* __restrict__ HTb, int coloff) {
    constexpr int L = F / 2;
    constexpr int NPB = 256 / L;
    int t = threadIdx.x;
    int g = t / L, c2 = t % L;
    int node = blockIdx.x * NPB + g;
    int e0 = off[node], e1 = off[node + 1];
    int deg = e1 - e0;
    const int* srow = edges + e0;
    float a0 = 0.0f, a1 = 0.0f;
    int e = 0;
    for (; e + 3 < deg; e += 4) {
        int s0 = srow[e], s1 = srow[e + 1], s2 = srow[e + 2], s3 = srow[e + 3];
        uint_t u0 = y[(size_t)s0 * L + c2];
        uint_t u1 = y[(size_t)s1 * L + c2];
        uint_t u2 = y[(size_t)s2 * L + c2];
        uint_t u3 = y[(size_t)s3 * L + c2];
        a0 += __uint_as_float(u0 << 16) + __uint_as_float(u1 << 16)
            + __uint_as_float(u2 << 16) + __uint_as_float(u3 << 16);
        a1 += __uint_as_float(u0 & 0xFFFF0000u) + __uint_as_float(u1 & 0xFFFF0000u)
            + __uint_as_float(u2 & 0xFFFF0000u) + __uint_as_float(u3 & 0xFFFF0000u);
    }
    for (; e < deg; e++) {
        uint_t u = y[(size_t)srow[e] * L + c2];
        a0 += __uint_as_float(u << 16);
        a1 += __uint_as_float(u & 0xFFFF0000u);
    }
    float dn = rsqrtf(fmaxf((float)deg, 1.0f));
    float v0 = a0 * dn + bias[2 * c2];
    float v1 = a1 * dn + bias[2 * c2 + 1];
    if (RELU) { v0 = fmaxf(v0, 0.0f); v1 = fmaxf(v1, 0.0f); }
    HTb[(size_t)(coloff + 2 * c2) * NN + node] = (ushort_t)f2bf(v0);
    HTb[(size_t)(coloff + 2 * c2 + 1) * NN + node] = (ushort_t)f2bf(v1);
}

// ---------------- pooling v12: MFMA + XCD-chunk swizzle + compile-time trip ----------------
// r17 lessons: (a) runtime trip count defeated unrolling (VGPR stuck at 28, ~6 loads in
// flight); (b) PNK 32 raised FETCH 425->530MB because same-ky blocks spread across XCDs
// re-fetch the same 307KB HTb chunk per-XCD. Fixes:
// (1) 1D grid + XCD-aware remap: ky = (L%8)*4 + (L/8)%4, mat = (L/32)%2, bx = L/64 --
//     blocks sharing (ky,mat) land on one XCD (assuming XCD = linear%8 round-robin; if the
//     mapping guess is wrong it only costs speed, not correctness). HTb HBM ~150->~20MB.
// (2) full chunks (ky<31) take a CONSTANT 25-halfstep loop with #pragma unroll 5 ->
//     compiler batches 15 loads per group (VGPR up, deep MLP). Last chunk: dynamic+tail.
// Frag layouts (guide §3, m89-verified): A lane l -> row l&15, k=(l>>4)*8+i; B lane l ->
// col l&15, same k; C/D lane l reg r -> row (l>>4)*4+r, col l&15.
__global__ __launch_bounds__(384) void k_pool10(
        const float* __restrict__ lenA, const float* __restrict__ lenB,
        const ushort_t* __restrict__ HTbA, const ushort_t* __restrict__ HTbB,
        float* __restrict__ pooled) {
    __shared__ float red[3][64][4];
    const int L = blockIdx.x;
    const int bx  = L >> 6;
    const int rem = L & 63;
    const int ky  = ((rem & 7) << 2) | ((rem >> 3) & 3);
    const int mat = (rem >> 5) & 1;
    const float* __restrict__ len = mat ? lenB : lenA;
    const ushort_t* __restrict__ HTb = mat ? HTbB : HTbA;
    const int colbase = mat ? 48 : 0;
    const int b0 = bx * 16;
    const int w = threadIdx.x >> 6;   // 0..5
    const int l = threadIdx.x & 63;
    const int c = w >> 1;             // col tile 0..2
    const int kh = w & 1;             // k-partner (even/odd 64-k blocks)
    const int rc = l & 15;
    const int seg = l >> 4;           // 0..3

    const int kc0 = ky * PK;
    const int kend = (kc0 + PK < NN) ? (kc0 + PK) : NN;
    const float* lrow = len + (size_t)(b0 + rc) * NN;          // A row (graph b0+rc)
    const ushort_t* hrow = HTb + (size_t)(c * 16 + rc) * NN;   // B col (HTb row)

    f32x4v acc = {0.0f, 0.0f, 0.0f, 0.0f};

    const int kw0 = kc0 + kh * 64;            // this wave's first 64-k halfstep
    const int lb0 = kw0 + seg * 8;            // this lane's base

    if (kend == kc0 + PK) {
        // full chunk: compile-time 25 halfsteps
#pragma unroll 5
        for (int t = 0; t < PK / 128; t++) {
            int kb = lb0 + t * 128;
#pragma unroll
            for (int h = 0; h < 2; h++) {
                f32x4v a0 = *(const f32x4v*)(lrow + kb + h * 32);
                f32x4v a1 = *(const f32x4v*)(lrow + kb + h * 32 + 4);
                short8v b = *(const short8v*)(hrow + kb + h * 32);
                short8v a;
                a[0] = f2bf(a0.x); a[1] = f2bf(a0.y); a[2] = f2bf(a0.z); a[3] = f2bf(a0.w);
                a[4] = f2bf(a1.x); a[5] = f2bf(a1.y); a[6] = f2bf(a1.z); a[7] = f2bf(a1.w);
                acc = __builtin_amdgcn_mfma_f32_16x16x32_bf16(a, b, acc, 0, 0, 0);
            }
        }
    } else {
        int avail = kend - kw0;
        int Tfull = (avail >= 64) ? ((avail - 64) >> 7) + 1 : 0;
        for (int t = 0; t < Tfull; t++) {
            int kb = lb0 + t * 128;
#pragma unroll
            for (int h = 0; h < 2; h++) {
                f32x4v a0 = *(const f32x4v*)(lrow + kb + h * 32);
                f32x4v a1 = *(const f32x4v*)(lrow + kb + h * 32 + 4);
                short8v b = *(const short8v*)(hrow + kb + h * 32);
                short8v a;
                a[0] = f2bf(a0.x); a[1] = f2bf(a0.y); a[2] = f2bf(a0.z); a[3] = f2bf(a0.w);
                a[4] = f2bf(a1.x); a[5] = f2bf(a1.y); a[6] = f2bf(a1.z); a[7] = f2bf(a1.w);
                acc = __builtin_amdgcn_mfma_f32_16x16x32_bf16(a, b, acc, 0, 0, 0);
            }
        }
        // guarded tail halfstep; 8|NN and 8|kend -> a lane's 8-seg valid iff kb < kend
        int kt = kw0 + Tfull * 128;
        if (kt < kend) {
#pragma unroll
            for (int h = 0; h < 2; h++) {
                int kb = kt + h * 32 + seg * 8;
                short8v a = (short8v)0, b = (short8v)0;
                if (kb < kend) {
                    f32x4v a0 = *(const f32x4v*)(lrow + kb);
                    f32x4v a1 = *(const f32x4v*)(lrow + kb + 4);
                    a[0] = f2bf(a0.x); a[1] = f2bf(a0.y); a[2] = f2bf(a0.z); a[3] = f2bf(a0.w);
                    a[4] = f2bf(a1.x); a[5] = f2bf(a1.y); a[6] = f2bf(a1.z); a[7] = f2bf(a1.w);
                    b = *(const short8v*)(hrow + kb);
                }
                acc = __builtin_amdgcn_mfma_f32_16x16x32_bf16(a, b, acc, 0, 0, 0);
            }
        }
    }

    if (kh == 1) {
        *(f32x4v*)&red[c][l][0] = acc;
    }
    __syncthreads();
    if (kh == 0) {
        f32x4v o = *(const f32x4v*)&red[c][l][0];
#pragma unroll
        for (int r = 0; r < 4; r++) {
            float v = acc[r] + o[r];
            atomicAdd(&pooled[(b0 + seg * 4 + r) * 96 + colbase + c * 16 + rc], v);
        }
    }
}

// ---------------- MLP head ----------------
__global__ void k_mlp(const float* __restrict__ pooled,
                      const float* __restrict__ fc1w, const float* __restrict__ fc1b,
                      const float* __restrict__ fc2w, const float* __restrict__ fc2b,
                      const float* __restrict__ fc3w, const float* __restrict__ fc3b,
                      float* __restrict__ out) {
    __shared__ float srow[96];
    __shared__ float sh[64];
    __shared__ float sh2[16];
    int b = blockIdx.x, t = threadIdx.x; // 64 threads
    srow[t] = pooled[b * 96 + t];
    if (t < 32) srow[64 + t] = pooled[b * 96 + 64 + t];
    __syncthreads();
    float acc = fc1b[t];
    for (int k = 0; k < 96; k++) acc += srow[k] * fc1w[k * 64 + t];
    sh[t] = fmaxf(acc, 0.0f);
    __syncthreads();
    if (t < 16) {
        float a2 = fc2b[t];
        for (int k = 0; k < 64; k++) a2 += sh[k] * fc2w[k * 16 + t];
        sh2[t] = fmaxf(a2, 0.0f);
    }
    __syncthreads();
    if (t == 0) {
        float a3 = fc3b[0];
        for (int k = 0; k < 16; k++) a3 += sh2[k] * fc3w[k];
        out[b] = a3;
    }
}

extern "C" void kernel_launch(void* const* d_in, const int* in_sizes, int n_in,
                              void* d_out, int out_size, void* d_ws, size_t ws_size,
                              hipStream_t stream) {
    const float* solute_x  = (const float*)d_in[0];
    const float* solvent_x = (const float*)d_in[1];
    const float* su_len    = (const float*)d_in[2];
    const float* sv_len    = (const float*)d_in[3];
    const int*   su_src    = (const int*)d_in[4];
    const int*   su_dst    = (const int*)d_in[5];
    const int*   sv_src    = (const int*)d_in[6];
    const int*   sv_dst    = (const int*)d_in[7];
    const float* W1  = (const float*)d_in[8];
    const float* b1  = (const float*)d_in[9];
    const float* W2  = (const float*)d_in[10];
    const float* b2  = (const float*)d_in[11];
    const float* fc1w = (const float*)d_in[12];
    const float* fc1b = (const float*)d_in[13];
    const float* fc2w = (const float*)d_in[14];
    const float* fc2b = (const float*)d_in[15];
    const float* fc3w = (const float*)d_in[16];
    const float* fc3b = (const float*)d_in[17];
    float* out = (float*)d_out;

    // ---- arena (4B words), total ~70.8 MB ----
    char* ws = (char*)d_ws;
    size_t o = 0;
    auto alloc = [&](size_t elems) { void* p = ws + o * 4; o += elems; return p; };
    int* cnt4     = (int*)alloc((size_t)4 * NBLK * NBINS);  // [D_su][S_su][D_sv][S_sv]
    int* binTot   = (int*)alloc(4 * NBINS);
    int* binBase  = (int*)alloc(4 * (NBINS + 1));
    int* off_su   = (int*)alloc(NN + 1);
    int* off_sv   = (int*)alloc(NN + 1);
    int* csrc_su  = (int*)alloc(NN);
    int* csrc_sv  = (int*)alloc(NN);
    float* pooled = (float*)alloc(NB * 96);
    int* edges_su = (int*)alloc(NE);
    int* edges_sv = (int*)alloc(NE);
    o = (o + 1) & ~(size_t)1;                 // 8B align for int2
    // union region X: build {sortedD int2 NE = 25.6MB, sortedS int NE = 12.8MB} = 38.4MB
    //                 compute {ybuf 6.4MB + HTb_su 9.6MB + HTb_sv 9.6MB} = 25.6MB
    char* X = ws + o * 4;
    int2*     sortedD = (int2*)X;
    int*      sortedS = (int*)(X + (size_t)NE * 8);
    uint_t*   ybuf    = (uint_t*)X;
    ushort_t* HTb_su  = (ushort_t*)(X + (size_t)NN * 64);
    ushort_t* HTb_sv  = (ushort_t*)(X + (size_t)NN * 160);

    hipMemsetAsync(binTot, 0, 4 * NBINS * 4, stream);
    hipMemsetAsync(pooled, 0, NB * 96 * 4, stream);

    // ==== phase 1: histograms + scans for BOTH graphs in merged launches ====
    k_p1<<<2 * NBLK, 256, 0, stream>>>(su_src, su_dst, sv_src, sv_dst, cnt4, binTot);
    k_scanA<<<4, 256, 0, stream>>>(binTot, binBase, off_su, off_sv);
    k_scanB<<<4 * NBINS, 256, 0, stream>>>(cnt4, binBase);

    const int* g_src[2]  = {su_src, sv_src};
    const int* g_dst[2]  = {su_dst, sv_dst};
    int* g_off[2]        = {off_su, off_sv};
    int* g_edges[2]      = {edges_su, edges_sv};
    int* g_csrc[2]       = {csrc_su, csrc_sv};

    // per-graph: scatter + counting-sort (sorted buffers reused sequentially)
    for (int g = 0; g < 2; g++) {
        const int* cntD = cnt4 + (size_t)(2 * g) * NBLK * NBINS;
        const int* cntS = cnt4 + (size_t)(2 * g + 1) * NBLK * NBINS;
        const int* bbD  = binBase + (2 * g) * (NBINS + 1);
        const int* bbS  = binBase + (2 * g + 1) * (NBINS + 1);
        k_p3<<<NBLK, 256, 0, stream>>>(g_src[g], g_dst[g], cntD, cntS, sortedD, sortedS);
        k_p4<<<2 * NBINS, 256, 0, stream>>>(sortedD, sortedS, bbD, bbS,
                                            g_off[g], g_edges[g], g_csrc[g]);
    }

    // ==== phase 2: GCN layers (sorted buffers dead; ybuf/HTb take over region X) ====
    const float* g_x[2]  = {solute_x, solvent_x};
    ushort_t* g_HTb[2]   = {HTb_su, HTb_sv};
    for (int g = 0; g < 2; g++) {
        k_t1<<<NN / 8, 256, 0, stream>>>(g_x[g], W1, g_csrc[g], (ushort_t*)ybuf);
        k_agg<32, 1><<<NN / 16, 256, 0, stream>>>(ybuf, g_off[g], g_edges[g], b1, g_HTb[g], 0);
        k_t2<<<NN / 16, 256, 0, stream>>>(g_HTb[g], W2, g_csrc[g], (ushort_t*)ybuf);
        k_agg<16, 0><<<NN / 32, 256, 0, stream>>>(ybuf, g_off[g], g_edges[g], b2, g_HTb[g], 32);
    }

    // ==== pooling (MFMA, XCD-swizzled 1D grid) + MLP ====
    k_pool10<<<(NB / 16) * PNK * 2, 384, 0, stream>>>(su_len, sv_len, HTb_su, HTb_sv, pooled);
    k_mlp<<<NB, 64, 0, stream>>>(pooled, fc1w, fc1b, fc2w, fc2b, fc3w, fc3b, out);
}

// Round 19
// 706.576 us; speedup vs baseline: 1.1015x; 1.0974x over previous
//
#include <hip/hip_runtime.h>
#include <hip/hip_bf16.h>

#define NN 100000
#define NE 3200000
#define NB 512
#define BINW 128                  // nodes per bin (bin = node >> 7)
#define NBINS 782                 // ceil(NN / 128); 782*128 = 100096
#define EPB 8192                  // edges per p1/p3 block
#define NBLK 391                  // ceil(NE / EPB)
#define PK 6272                   // pool k-chunk (r16-proven best: 16*6272 = 100352 >= NN)
#define PNK 16

typedef unsigned short ushort_t;
typedef unsigned int uint_t;
typedef unsigned char uchar_t;
typedef __attribute__((ext_vector_type(8))) short short8v;   // 8 bf16 (4 VGPRs)
typedef __attribute__((ext_vector_type(4))) float f32x4v;

static __device__ __forceinline__ short f2bf(float f) {
    __hip_bfloat16 h = __float2bfloat16(f);
    return *reinterpret_cast<short*>(&h);
}
static __device__ __forceinline__ float bf2f(ushort_t u) {
    return __uint_as_float(((uint_t)u) << 16);
}

// ---------------- p1: per-block bin-histograms (dst AND src), BOTH graphs ----------------
__global__ __launch_bounds__(256) void k_p1(const int* __restrict__ srcA,
                                            const int* __restrict__ dstA,
                                            const int* __restrict__ srcB,
                                            const int* __restrict__ dstB,
                                            int* __restrict__ cnt4,
                                            int* __restrict__ binTot) {
    __shared__ int hD[NBINS], hS[NBINS];
    int t = threadIdx.x, b = blockIdx.x;
    int g = (b >= NBLK) ? 1 : 0;
    int bb = b - g * NBLK;
    const int* src = g ? srcB : srcA;
    const int* dst = g ? dstB : dstA;
    int* cntD = cnt4 + (size_t)(2 * g)     * NBLK * NBINS;
    int* cntS = cnt4 + (size_t)(2 * g + 1) * NBLK * NBINS;
    int* btD  = binTot + (2 * g) * NBINS;
    int* btS  = binTot + (2 * g + 1) * NBINS;
    for (int i = t; i < NBINS; i += 256) { hD[i] = 0; hS[i] = 0; }
    __syncthreads();
    int base = bb * EPB;
#pragma unroll
    for (int i = 0; i < EPB / 1024; i++) {
        int idx = base + i * 1024 + t * 4;
        if (idx < NE) {  // NE%4==0 -> whole int4 valid
            int4 d4 = *(const int4*)(dst + idx);
            int4 s4 = *(const int4*)(src + idx);
            atomicAdd(&hD[d4.x >> 7], 1); atomicAdd(&hD[d4.y >> 7], 1);
            atomicAdd(&hD[d4.z >> 7], 1); atomicAdd(&hD[d4.w >> 7], 1);
            atomicAdd(&hS[s4.x >> 7], 1); atomicAdd(&hS[s4.y >> 7], 1);
            atomicAdd(&hS[s4.z >> 7], 1); atomicAdd(&hS[s4.w >> 7], 1);
        }
    }
    __syncthreads();
    for (int i = t; i < NBINS; i += 256) {
        int vD = hD[i]; cntD[(size_t)bb * NBINS + i] = vD; if (vD) atomicAdd(btD + i, vD);
        int vS = hS[i]; cntS[(size_t)bb * NBINS + i] = vS; if (vS) atomicAdd(btS + i, vS);
    }
}

// ---------------- scanA: exclusive scan of bin totals, 4 units ----------------
__global__ void k_scanA(const int* __restrict__ binTot, int* __restrict__ binBase,
                        int* __restrict__ off_su, int* __restrict__ off_sv) {
    __shared__ int s[NBINS];
    int u = blockIdx.x;  // 0=D_su 1=S_su 2=D_sv 3=S_sv
    const int* bt = binTot + u * NBINS;
    int* bb = binBase + u * (NBINS + 1);
    int t = threadIdx.x;
    for (int i = t; i < NBINS; i += 256) s[i] = bt[i];
    __syncthreads();
    if (t == 0) {
        int acc = 0;
        for (int i = 0; i < NBINS; i++) { int v = s[i]; s[i] = acc; acc += v; }
    }
    __syncthreads();
    for (int i = t; i < NBINS; i += 256) bb[i] = s[i];
    if (t == 0) bb[NBINS] = NE;
    if (t == 0 && u == 0) { off_su[NN] = NE; off_sv[NN] = NE; }
}

// ---------------- scanB: per-bin prefix over blocks, IN PLACE in cnt ----------------
__global__ void k_scanB(int* __restrict__ cnt4, const int* __restrict__ binBase) {
    __shared__ int s[NBLK];
    int u = blockIdx.x / NBINS, j = blockIdx.x % NBINS;
    int* cnt = cnt4 + (size_t)u * NBLK * NBINS;
    const int* bb = binBase + u * (NBINS + 1);
    int t = threadIdx.x;
    for (int i = t; i < NBLK; i += 256) s[i] = cnt[(size_t)i * NBINS + j];
    __syncthreads();
    if (t == 0) {
        int acc = bb[j];
        for (int i = 0; i < NBLK; i++) { int v = s[i]; s[i] = acc; acc += v; }
    }
    __syncthreads();
    for (int i = t; i < NBLK; i += 256) cnt[(size_t)i * NBINS + j] = s[i];
}

// ---------------- p3: dual scatter into bin order, BOTH graphs, packed payloads --------
// sortedD entry = src | (dst&127)<<20  (src<2^17; one int instead of int2: half traffic)
// sortedS entry = (uchar)(src&127)     (only the in-bin id is ever used: 1B instead of 4B)
__global__ __launch_bounds__(256) void k_p3(const int* __restrict__ srcA,
                                            const int* __restrict__ dstA,
                                            const int* __restrict__ srcB,
                                            const int* __restrict__ dstB,
                                            const int* __restrict__ cnt4,
                                            int* __restrict__ sdA, int* __restrict__ sdB,
                                            uchar_t* __restrict__ ssA,
                                            uchar_t* __restrict__ ssB) {
    __shared__ int curD[NBINS], curS[NBINS];
    int t = threadIdx.x, b = blockIdx.x;
    int g = (b >= NBLK) ? 1 : 0;
    int bb = b - g * NBLK;
    const int* src = g ? srcB : srcA;
    const int* dst = g ? dstB : dstA;
    const int* cntD = cnt4 + (size_t)(2 * g)     * NBLK * NBINS;
    const int* cntS = cnt4 + (size_t)(2 * g + 1) * NBLK * NBINS;
    int* sd = g ? sdB : sdA;
    uchar_t* ss = g ? ssB : ssA;
    for (int i = t; i < NBINS; i += 256) {
        curD[i] = cntD[(size_t)bb * NBINS + i];
        curS[i] = cntS[(size_t)bb * NBINS + i];
    }
    __syncthreads();
    int base = bb * EPB;
#pragma unroll
    for (int i = 0; i < EPB / 1024; i++) {
        int idx = base + i * 1024 + t * 4;
        if (idx < NE) {
            int4 s4 = *(const int4*)(src + idx);
            int4 d4 = *(const int4*)(dst + idx);
            int p;
            p = atomicAdd(&curD[d4.x >> 7], 1); sd[p] = s4.x | ((d4.x & 127) << 20);
            p = atomicAdd(&curD[d4.y >> 7], 1); sd[p] = s4.y | ((d4.y & 127) << 20);
            p = atomicAdd(&curD[d4.z >> 7], 1); sd[p] = s4.z | ((d4.z & 127) << 20);
            p = atomicAdd(&curD[d4.w >> 7], 1); sd[p] = s4.w | ((d4.w & 127) << 20);
            p = atomicAdd(&curS[s4.x >> 7], 1); ss[p] = (uchar_t)(s4.x & 127);
            p = atomicAdd(&curS[s4.y >> 7], 1); ss[p] = (uchar_t)(s4.y & 127);
            p = atomicAdd(&curS[s4.z >> 7], 1); ss[p] = (uchar_t)(s4.z & 127);
            p = atomicAdd(&curS[s4.w >> 7], 1); ss[p] = (uchar_t)(s4.w & 127);
        }
    }
}

// ---------------- p4: [0,2N) D counting-sort -> CSR per graph; [2N,4N) S hist ----------
__global__ __launch_bounds__(256) void k_p4(const int* __restrict__ sdA,
                                            const int* __restrict__ sdB,
                                            const uchar_t* __restrict__ ssA,
                                            const uchar_t* __restrict__ ssB,
                                            const int* __restrict__ binBase,
                                            int* __restrict__ offA, int* __restrict__ offB,
                                            int* __restrict__ edgesA,
                                            int* __restrict__ edgesB,
                                            int* __restrict__ csA, int* __restrict__ csB) {
    __shared__ int hist[BINW], pre[BINW], cur[BINW];
    int t = threadIdx.x;
    int u = blockIdx.x / NBINS, bin = blockIdx.x % NBINS;
    if (u < 2) {
        const int* sd = u ? sdB : sdA;
        const int* bb = binBase + (2 * u) * (NBINS + 1);
        int* off   = u ? offB : offA;
        int* edges = u ? edgesB : edgesA;
        if (t < BINW) hist[t] = 0;
        __syncthreads();
        int e0 = bb[bin], e1 = bb[bin + 1];
        for (int e = e0 + t; e < e1; e += 256)
            atomicAdd(&hist[sd[e] >> 20], 1);
        __syncthreads();
        if (t == 0) {
            int a = 0;
            for (int i = 0; i < BINW; i++) { pre[i] = a; a += hist[i]; }
        }
        __syncthreads();
        if (t < BINW) {
            cur[t] = pre[t];
            int node = bin * BINW + t;
            if (node < NN) off[node] = e0 + pre[t];
        }
        __syncthreads();
        for (int e = e0 + t; e < e1; e += 256) {
            int v = sd[e];
            int p = atomicAdd(&cur[v >> 20], 1);
            edges[e0 + p] = v & 0xFFFFF;
        }
    } else {
        const uchar_t* ss = (u == 3) ? ssB : ssA;
        const int* bb = binBase + (2 * (u - 2) + 1) * (NBINS + 1);
        int* cs = (u == 3) ? csB : csA;
        if (t < BINW) hist[t] = 0;
        __syncthreads();
        int e0 = bb[bin], e1 = bb[bin + 1];
        for (int e = e0 + t; e < e1; e += 256)
            atomicAdd(&hist[ss[e]], 1);
        __syncthreads();
        if (t < BINW) {
            int node = bin * BINW + t;
            if (node < NN) cs[node] = hist[t];
        }
    }
}

// ---------------- t1 (both graphs): y = (x*sn)@W1 (bf16) ----------------
__global__ __launch_bounds__(256) void k_t1(const float* __restrict__ xA,
                                            const float* __restrict__ xB,
                                            const float* __restrict__ W1,
                                            const int* __restrict__ csA,
                                            const int* __restrict__ csB,
                                            ushort_t* __restrict__ yA,
                                            ushort_t* __restrict__ yB) {
    __shared__ float sW[2048];
    __shared__ float sx[8 * 65];
    int g = blockIdx.y;
    const float* x = g ? xB : xA;
    const int* cnt_src = g ? csB : csA;
    ushort_t* y = g ? yB : yA;
    int t = threadIdx.x;
    int node0 = blockIdx.x * 8;
    for (int i = t; i < 2048; i += 256) sW[i] = W1[i];
    for (int i = t; i < 512; i += 256) {
        int r = i >> 6, k = i & 63;
        sx[r * 65 + k] = x[(size_t)(node0 + r) * 64 + k];
    }
    __syncthreads();
    int r = t >> 5, c = t & 31;
    int node = node0 + r;
    float sn = rsqrtf(fmaxf((float)cnt_src[node], 1.0f));
    float acc = 0.0f;
#pragma unroll
    for (int k = 0; k < 64; k++) acc += sx[r * 65 + k] * sW[k * 32 + c];
    acc *= sn;   // row scalar commutes with @W1
    y[(size_t)node * 32 + c] = (ushort_t)f2bf(acc);
}

// ---------------- t2 (both graphs): y2 = (HTb_rows(0..31)*sn)@W2 ----------------
__global__ __launch_bounds__(256) void k_t2(const ushort_t* __restrict__ HTbA,
                                            const ushort_t* __restrict__ HTbB,
                                            const float* __restrict__ W2,
                                            const int* __restrict__ csA,
                                            const int* __restrict__ csB,
                                            ushort_t* __restrict__ yA,
                                            ushort_t* __restrict__ yB) {
    __shared__ float sW[512];
    __shared__ float sx[16 * 33];
    int g = blockIdx.y;
    const ushort_t* HTb = g ? HTbB : HTbA;
    const int* cnt_src = g ? csB : csA;
    ushort_t* y2 = g ? yB : yA;
    int t = threadIdx.x;
    int node0 = blockIdx.x * 16;
    for (int i = t; i < 512; i += 256) sW[i] = W2[i];
    for (int i = t; i < 512; i += 256) {
        int r = i & 15, k = i >> 4;  // r fast -> coalesced over node dim
        sx[r * 33 + k] = bf2f(HTb[(size_t)k * NN + node0 + r]);
    }
    __syncthreads();
    int r = t >> 4, c = t & 15;
    int node = node0 + r;
    float sn = rsqrtf(fmaxf((float)cnt_src[node], 1.0f));
    float acc = 0.0f;
#pragma unroll
    for (int k = 0; k < 32; k++) acc += sx[r * 33 + k] * sW[k * 16 + c];
    acc *= sn;
    y2[(size_t)node * 16 + c] = (ushort_t)f2bf(acc);
}

// ---------------- CSR gather aggregation (both graphs), packed-uint y ----------------
template <int F, int RELU>
__global__ __launch_bounds__(256) void k_agg(
        const uint_t* __restrict__ yA, const uint_t* __restrict__ yB,
        const int* __restrict__ offA, const int* __restrict__ offB,
        const int* __restrict__ edgesA, const int* __restrict__ edgesB,
        const float* __restrict__ bias,
        ushort_t* __restrict__ HTbA, ushort_t* __restrict__ HTbB, int coloff) {
    constexpr int L = F / 2;
    constexpr int NPB = 256 / L;
    int gsel = blockIdx.y;
    const uint_t* y = gsel ? yB : yA;
    const int* off = gsel ? offB : offA;
    const int* edges = gsel ? edgesB : edgesA;
    ushort_t* HTb = gsel ? HTbB : HTbA;
    int t = threadIdx.x;
    int g = t / L, c2 = t % L;
    int node = blockIdx.x * NPB + g;
    int e0 = off[node], e1 = off[node + 1];
    int deg = e1 - e0;
    const int* srow = edges + e0;
    float a0 = 0.0f, a1 = 0.0f;
    int e = 0;
    for (; e + 3 < deg; e += 4) {
        int s0 = srow[e], s1 = srow[e + 1], s2 = srow[e + 2], s3 = srow[e + 3];
        uint_t u0 = y[(size_t)s0 * L + c2];
        uint_t u1 = y[(size_t)s1 * L + c2];
        uint_t u2 = y[(size_t)s2 * L + c2];
        uint_t u3 = y[(size_t)s3 * L + c2];
        a0 += __uint_as_float(u0 << 16) + __uint_as_float(u1 << 16)
            + __uint_as_float(u2 << 16) + __uint_as_float(u3 << 16);
        a1 += __uint_as_float(u0 & 0xFFFF0000u) + __uint_as_float(u1 & 0xFFFF0000u)
            + __uint_as_float(u2 & 0xFFFF0000u) + __uint_as_float(u3 & 0xFFFF0000u);
    }
    for (; e < deg; e++) {
        uint_t u = y[(size_t)srow[e] * L + c2];
        a0 += __uint_as_float(u << 16);
        a1 += __uint_as_float(u & 0xFFFF0000u);
    }
    float dn = rsqrtf(fmaxf((float)deg, 1.0f));
    float v0 = a0 * dn + bias[2 * c2];
    float v1 = a1 * dn + bias[2 * c2 + 1];
    if (RELU) { v0 = fmaxf(v0, 0.0f); v1 = fmaxf(v1, 0.0f); }
    HTb[(size_t)(coloff + 2 * c2) * NN + node] = (ushort_t)f2bf(v0);
    HTb[(size_t)(coloff + 2 * c2 + 1) * NN + node] = (ushort_t)f2bf(v1);
}

// ---------------- pooling: MFMA, r16-proven config (best measured: 207us) ----------------
// PNK16/PK6272, guard-free dynamic Tfull loop + guarded tail, unroll 2, 3D grid.
// r17/r18 lessons: PNK32 raised FETCH (cross-XCD HTb re-fetch); XCD swizzle + const-trip
// unroll cut FETCH but thrashed per-XCD L2 on len panels and didn't deepen the load
// window (VGPR pinned at 28 by the compiler) -> both reverted.
// Frag layouts (guide §3, m89-verified): A lane l -> row l&15, k=(l>>4)*8+i; B lane l ->
// col l&15, same k; C/D lane l reg r -> row (l>>4)*4+r, col l&15.
__global__ __launch_bounds__(384) void k_pool9(
        const float* __restrict__ lenA, const float* __restrict__ lenB,
        const ushort_t* __restrict__ HTbA, const ushort_t* __restrict__ HTbB,
        float* __restrict__ pooled) {
    __shared__ float red[3][64][4];
    const int mat = blockIdx.z;
    const float* __restrict__ len = mat ? lenB : lenA;
    const ushort_t* __restrict__ HTb = mat ? HTbB : HTbA;
    const int colbase = mat ? 48 : 0;
    const int b0 = blockIdx.x * 16;
    const int w = threadIdx.x >> 6;   // 0..5
    const int l = threadIdx.x & 63;
    const int c = w >> 1;             // col tile 0..2
    const int kh = w & 1;             // k-partner (even/odd 64-k blocks)
    const int rc = l & 15;
    const int seg = l >> 4;           // 0..3

    const int kc0 = blockIdx.y * PK;
    const int kend = (kc0 + PK < NN) ? (kc0 + PK) : NN;
    const float* lrow = len + (size_t)(b0 + rc) * NN;          // A row (graph b0+rc)
    const ushort_t* hrow = HTb + (size_t)(c * 16 + rc) * NN;   // B col (HTb row)

    f32x4v acc = {0.0f, 0.0f, 0.0f, 0.0f};

    const int kw0 = kc0 + kh * 64;            // this wave's first 64-k halfstep
    const int lb0 = kw0 + seg * 8;            // this lane's base
    int avail = kend - kw0;
    int Tfull = (avail >= 64) ? ((avail - 64) >> 7) + 1 : 0;  // halfsteps fully in range

#pragma unroll 2
    for (int t = 0; t < Tfull; t++) {
        int kb = lb0 + t * 128;
#pragma unroll
        for (int h = 0; h < 2; h++) {
            f32x4v a0 = *(const f32x4v*)(lrow + kb + h * 32);
            f32x4v a1 = *(const f32x4v*)(lrow + kb + h * 32 + 4);
            short8v b = *(const short8v*)(hrow + kb + h * 32);
            short8v a;
            a[0] = f2bf(a0.x); a[1] = f2bf(a0.y); a[2] = f2bf(a0.z); a[3] = f2bf(a0.w);
            a[4] = f2bf(a1.x); a[5] = f2bf(a1.y); a[6] = f2bf(a1.z); a[7] = f2bf(a1.w);
            acc = __builtin_amdgcn_mfma_f32_16x16x32_bf16(a, b, acc, 0, 0, 0);
        }
    }

    // guarded tail halfstep (only the last k-chunk reaches here); 8|NN and 8|kend ->
    // a lane's 8-seg is valid iff kb < kend
    int kt = kw0 + Tfull * 128;
    if (kt < kend) {
#pragma unroll
        for (int h = 0; h < 2; h++) {
            int kb = kt + h * 32 + seg * 8;
            short8v a = (short8v)0, b = (short8v)0;
            if (kb < kend) {
                f32x4v a0 = *(const f32x4v*)(lrow + kb);
                f32x4v a1 = *(const f32x4v*)(lrow + kb + 4);
                a[0] = f2bf(a0.x); a[1] = f2bf(a0.y); a[2] = f2bf(a0.z); a[3] = f2bf(a0.w);
                a[4] = f2bf(a1.x); a[5] = f2bf(a1.y); a[6] = f2bf(a1.z); a[7] = f2bf(a1.w);
                b = *(const short8v*)(hrow + kb);
            }
            acc = __builtin_amdgcn_mfma_f32_16x16x32_bf16(a, b, acc, 0, 0, 0);
        }
    }

    if (kh == 1) {
        *(f32x4v*)&red[c][l][0] = acc;
    }
    __syncthreads();
    if (kh == 0) {
        f32x4v o = *(const f32x4v*)&red[c][l][0];
#pragma unroll
        for (int r = 0; r < 4; r++) {
            float v = acc[r] + o[r];
            atomicAdd(&pooled[(b0 + seg * 4 + r) * 96 + colbase + c * 16 + rc], v);
        }
    }
}

// ---------------- MLP head ----------------
__global__ void k_mlp(const float* __restrict__ pooled,
                      const float* __restrict__ fc1w, const float* __restrict__ fc1b,
                      const float* __restrict__ fc2w, const float* __restrict__ fc2b,
                      const float* __restrict__ fc3w, const float* __restrict__ fc3b,
                      float* __restrict__ out) {
    __shared__ float srow[96];
    __shared__ float sh[64];
    __shared__ float sh2[16];
    int b = blockIdx.x, t = threadIdx.x; // 64 threads
    srow[t] = pooled[b * 96 + t];
    if (t < 32) srow[64 + t] = pooled[b * 96 + 64 + t];
    __syncthreads();
    float acc = fc1b[t];
    for (int k = 0; k < 96; k++) acc += srow[k] * fc1w[k * 64 + t];
    sh[t] = fmaxf(acc, 0.0f);
    __syncthreads();
    if (t < 16) {
        float a2 = fc2b[t];
        for (int k = 0; k < 64; k++) a2 += sh[k] * fc2w[k * 16 + t];
        sh2[t] = fmaxf(a2, 0.0f);
    }
    __syncthreads();
    if (t == 0) {
        float a3 = fc3b[0];
        for (int k = 0; k < 16; k++) a3 += sh2[k] * fc3w[k];
        out[b] = a3;
    }
}

extern "C" void kernel_launch(void* const* d_in, const int* in_sizes, int n_in,
                              void* d_out, int out_size, void* d_ws, size_t ws_size,
                              hipStream_t stream) {
    const float* solute_x  = (const float*)d_in[0];
    const float* solvent_x = (const float*)d_in[1];
    const float* su_len    = (const float*)d_in[2];
    const float* sv_len    = (const float*)d_in[3];
    const int*   su_src    = (const int*)d_in[4];
    const int*   su_dst    = (const int*)d_in[5];
    const int*   sv_src    = (const int*)d_in[6];
    const int*   sv_dst    = (const int*)d_in[7];
    const float* W1  = (const float*)d_in[8];
    const float* b1  = (const float*)d_in[9];
    const float* W2  = (const float*)d_in[10];
    const float* b2  = (const float*)d_in[11];
    const float* fc1w = (const float*)d_in[12];
    const float* fc1b = (const float*)d_in[13];
    const float* fc2w = (const float*)d_in[14];
    const float* fc2b = (const float*)d_in[15];
    const float* fc3w = (const float*)d_in[16];
    const float* fc3b = (const float*)d_in[17];
    float* out = (float*)d_out;

    // ---- arena (4B words), total ~64.4 MB ----
    char* ws = (char*)d_ws;
    size_t o = 0;
    auto alloc = [&](size_t elems) { void* p = ws + o * 4; o += elems; return p; };
    int* cnt4     = (int*)alloc((size_t)4 * NBLK * NBINS);  // [D_su][S_su][D_sv][S_sv]
    int* binTot   = (int*)alloc(4 * NBINS);
    int* binBase  = (int*)alloc(4 * (NBINS + 1));
    int* off_su   = (int*)alloc(NN + 1);
    int* off_sv   = (int*)alloc(NN + 1);
    int* csrc_su  = (int*)alloc(NN);
    int* csrc_sv  = (int*)alloc(NN);
    float* pooled = (float*)alloc(NB * 96);
    int* edges_su = (int*)alloc(NE);
    int* edges_sv = (int*)alloc(NE);
    o = (o + 1) & ~(size_t)1;                 // 8B align
    // union region X (32 MB):
    //   build:   sdA int NE (12.8) | sdB int NE (12.8) | ssA uchar NE (3.2) | ssB (3.2)
    //   compute: ybuf_su 6.4 | ybuf_sv 6.4 | HTb_su 9.6 | HTb_sv 9.6
    char* X = ws + o * 4;
    int*      sdA     = (int*)X;
    int*      sdB     = (int*)(X + (size_t)NE * 4);
    uchar_t*  ssA     = (uchar_t*)(X + (size_t)NE * 8);
    uchar_t*  ssB     = (uchar_t*)(X + (size_t)NE * 9);
    uint_t*   ybuf_su = (uint_t*)X;
    uint_t*   ybuf_sv = (uint_t*)(X + (size_t)NN * 64);
    ushort_t* HTb_su  = (ushort_t*)(X + (size_t)NN * 128);
    ushort_t* HTb_sv  = (ushort_t*)(X + (size_t)NN * 128 + (size_t)NN * 96);

    hipMemsetAsync(binTot, 0, 4 * NBINS * 4, stream);
    hipMemsetAsync(pooled, 0, NB * 96 * 4, stream);

    // ==== phase 1: sort-based CSR build, both graphs, merged launches ====
    k_p1<<<2 * NBLK, 256, 0, stream>>>(su_src, su_dst, sv_src, sv_dst, cnt4, binTot);
    k_scanA<<<4, 256, 0, stream>>>(binTot, binBase, off_su, off_sv);
    k_scanB<<<4 * NBINS, 256, 0, stream>>>(cnt4, binBase);
    k_p3<<<2 * NBLK, 256, 0, stream>>>(su_src, su_dst, sv_src, sv_dst, cnt4,
                                       sdA, sdB, ssA, ssB);
    k_p4<<<4 * NBINS, 256, 0, stream>>>(sdA, sdB, ssA, ssB, binBase,
                                        off_su, off_sv, edges_su, edges_sv,
                                        csrc_su, csrc_sv);

    // ==== phase 2: GCN layers, both graphs per launch (sorted buffers now dead) ====
    {
        dim3 g1(NN / 8, 2);
        k_t1<<<g1, 256, 0, stream>>>(solute_x, solvent_x, W1, csrc_su, csrc_sv,
                                     (ushort_t*)ybuf_su, (ushort_t*)ybuf_sv);
        dim3 g2(NN / 16, 2);
        k_agg<32, 1><<<g2, 256, 0, stream>>>(ybuf_su, ybuf_sv, off_su, off_sv,
                                             edges_su, edges_sv, b1, HTb_su, HTb_sv, 0);
        k_t2<<<g2, 256, 0, stream>>>(HTb_su, HTb_sv, W2, csrc_su, csrc_sv,
                                     (ushort_t*)ybuf_su, (ushort_t*)ybuf_sv);
        dim3 g3(NN / 32, 2);
        k_agg<16, 0><<<g3, 256, 0, stream>>>(ybuf_su, ybuf_sv, off_su, off_sv,
                                             edges_su, edges_sv, b2, HTb_su, HTb_sv, 32);
    }

    // ==== pooling (MFMA) + MLP ====
    {
        dim3 gr(NB / 16, PNK, 2);
        k_pool9<<<gr, 384, 0, stream>>>(su_len, sv_len, HTb_su, HTb_sv, pooled);
    }
    k_mlp<<<NB, 64, 0, stream>>>(pooled, fc1w, fc1b, fc2w, fc2b, fc3w, fc3b, out);
}